// Round 1
// baseline (1750.742 us; speedup 1.0000x reference)
//
#include <hip/hip_runtime.h>
#include <stdint.h>

#define AS1C(p) ((const __attribute__((address_space(1))) void*)(p))
#define AS3(p)  ((__attribute__((address_space(3))) void*)(p))

typedef short bf16x8 __attribute__((ext_vector_type(8)));
typedef float f32x4  __attribute__((ext_vector_type(4)));

static __device__ __forceinline__ unsigned pack_bf16_2(float lo, float hi) {
  // two fp32 -> packed bf16x2 (truncation; systematic <0.4% scale error,
  // cancels in softmax/JSD to well below the 2% tolerance)
  return (__float_as_uint(lo) >> 16) | (__float_as_uint(hi) & 0xFFFF0000u);
}

// ---------------- fp32 -> bf16 convert (vectorized, grid-stride) -------------
__global__ __launch_bounds__(256) void cvt_f32_bf16(const float* __restrict__ in,
                                                    uint2* __restrict__ out,
                                                    long long n4) {
  long long i = (long long)blockIdx.x * blockDim.x + threadIdx.x;
  long long stride = (long long)gridDim.x * blockDim.x;
  const float4* in4 = (const float4*)in;
  for (; i < n4; i += stride) {
    float4 v = in4[i];
    uint2 o;
    o.x = pack_bf16_2(v.x, v.y);
    o.y = pack_bf16_2(v.z, v.w);
    out[i] = o;
  }
}

// ---------------- GEMM: C[M][N] = A[M][K] · B[N][K]^T ------------------------
// 128x128 tile, BK=64, 4 waves (2x2), 16x16x32 bf16 MFMA.
// MODE 0: A,B are bf16, staged via global_load_lds (16B).
// MODE 1: A,B are fp32, reg-staged with on-the-fly bf16 convert.
template<int MODE>
__global__ __launch_bounds__(256) void gemm_bt(const void* __restrict__ Av,
                                               const void* __restrict__ Bv,
                                               float* __restrict__ C,
                                               int N, int K) {
  __shared__ __align__(16) short sA[128 * 64];
  __shared__ __align__(16) short sB[128 * 64];
  const int t = threadIdx.x;
  const int lane = t & 63;
  const int wv = t >> 6;
  const int wm = wv >> 1, wn = wv & 1;
  const int rowA0 = blockIdx.x * 128;   // M-tile (fast dim: consecutive blocks share B panel)
  const int rowB0 = blockIdx.y * 128;   // N-tile (weight rows)

  f32x4 acc[4][4] = {};

  for (int k0 = 0; k0 < K; k0 += 64) {
    if constexpr (MODE == 0) {
      const short* A = (const short*)Av;
      const short* B = (const short*)Bv;
      #pragma unroll
      for (int i = 0; i < 4; ++i) {
        const int c = wv * 4 + i;             // wave-uniform LDS chunk (1024B)
        const int row = c * 8 + (lane >> 3);  // per-lane global row
        const int kk = (lane & 7) * 8;
        __builtin_amdgcn_global_load_lds(AS1C(A + (size_t)(rowA0 + row) * K + k0 + kk),
                                         AS3(sA + c * 512), 16, 0, 0);
        __builtin_amdgcn_global_load_lds(AS1C(B + (size_t)(rowB0 + row) * K + k0 + kk),
                                         AS3(sB + c * 512), 16, 0, 0);
      }
      asm volatile("s_waitcnt vmcnt(0)" ::: "memory");
    } else {
      const float* A = (const float*)Av;
      const float* B = (const float*)Bv;
      #pragma unroll
      for (int i = 0; i < 8; ++i) {
        const int o = i * 1024 + t * 4;       // element offset in 128x64 tile
        const int row = o >> 6;
        const int kk = o & 63;
        float4 va = *(const float4*)(A + (size_t)(rowA0 + row) * K + k0 + kk);
        float4 vb = *(const float4*)(B + (size_t)(rowB0 + row) * K + k0 + kk);
        uint2 pa, pb;
        pa.x = pack_bf16_2(va.x, va.y); pa.y = pack_bf16_2(va.z, va.w);
        pb.x = pack_bf16_2(vb.x, vb.y); pb.y = pack_bf16_2(vb.z, vb.w);
        *(uint2*)(sA + o) = pa;
        *(uint2*)(sB + o) = pb;
      }
    }
    __syncthreads();
    #pragma unroll
    for (int kk = 0; kk < 2; ++kk) {
      bf16x8 af[4], bfr[4];
      #pragma unroll
      for (int mi = 0; mi < 4; ++mi) {
        const int row = wm * 64 + mi * 16 + (lane & 15);
        af[mi] = *(const bf16x8*)&sA[row * 64 + kk * 32 + (lane >> 4) * 8];
      }
      #pragma unroll
      for (int ni = 0; ni < 4; ++ni) {
        const int col = wn * 64 + ni * 16 + (lane & 15);
        bfr[ni] = *(const bf16x8*)&sB[col * 64 + kk * 32 + (lane >> 4) * 8];
      }
      #pragma unroll
      for (int mi = 0; mi < 4; ++mi)
        #pragma unroll
        for (int ni = 0; ni < 4; ++ni)
          acc[mi][ni] = __builtin_amdgcn_mfma_f32_16x16x32_bf16(af[mi], bfr[ni],
                                                                acc[mi][ni], 0, 0, 0);
    }
    __syncthreads();
  }

  // Epilogue: C/D layout col=lane&15, row=(lane>>4)*4+r (m89-verified)
  #pragma unroll
  for (int mi = 0; mi < 4; ++mi) {
    #pragma unroll
    for (int ni = 0; ni < 4; ++ni) {
      const int col = rowB0 + wn * 64 + ni * 16 + (lane & 15);
      const int rowb = rowA0 + wm * 64 + mi * 16 + ((lane >> 4) * 4);
      #pragma unroll
      for (int r = 0; r < 4; ++r)
        C[(size_t)(rowb + r) * N + col] = acc[mi][ni][r];
    }
  }
}

// ---------------- per-row online max + log-sum-exp ---------------------------
__global__ __launch_bounds__(256) void rowstats(const float* __restrict__ L, int V,
                                                float* __restrict__ lseOut) {
  const int row = blockIdx.x;
  const float4* p = (const float4*)(L + (size_t)row * V);
  const int n4 = V >> 2;
  float m = -1e30f, s = 0.f;
  for (int i = threadIdx.x; i < n4; i += 256) {
    float4 v = p[i];
    float lm = fmaxf(fmaxf(v.x, v.y), fmaxf(v.z, v.w));
    if (lm > m) { s *= __expf(m - lm); m = lm; }
    s += __expf(v.x - m) + __expf(v.y - m) + __expf(v.z - m) + __expf(v.w - m);
  }
  #pragma unroll
  for (int off = 32; off > 0; off >>= 1) {
    float mo = __shfl_xor(m, off);
    float so = __shfl_xor(s, off);
    float mn = fmaxf(m, mo);
    s = s * __expf(m - mn) + so * __expf(mo - mn);
    m = mn;
  }
  __shared__ float sm[4], ss[4];
  const int w = threadIdx.x >> 6;
  if ((threadIdx.x & 63) == 0) { sm[w] = m; ss[w] = s; }
  __syncthreads();
  if (threadIdx.x == 0) {
    float M = sm[0], S = ss[0];
    for (int i = 1; i < 4; ++i) {
      float mn = fmaxf(M, sm[i]);
      S = S * __expf(M - mn) + ss[i] * __expf(sm[i] - mn);
      M = mn;
    }
    lseOut[row] = M + __logf(S);
  }
}

// ---------------- fused JSD + hard NLL over one row --------------------------
__global__ __launch_bounds__(256) void jsd_loss(const float* __restrict__ SL,
                                                const float* __restrict__ TL, int V,
                                                const float* __restrict__ sLse,
                                                const float* __restrict__ tLse,
                                                const int* __restrict__ labels,
                                                int rowOff, float* __restrict__ acc) {
  const int row = blockIdx.x;
  const float4* ps = (const float4*)(SL + (size_t)row * V);
  const float4* pt = (const float4*)(TL + (size_t)row * V);
  const float slse = sLse[rowOff + row];
  const float tlse = tLse[rowOff + row];
  const int lbl = labels[rowOff + row];   // -100 never matches a column -> auto-ignored
  float jsd = 0.f, hard = 0.f;
  const int n4 = V >> 2;
  auto term = [&](float sv, float tv, int colIdx) {
    float sl = sv - slse;
    float tl = tv - tlse;
    float sp = __expf(sl), tp = __expf(tl);
    float lm = __logf(0.5f * (sp + tp));
    jsd += 0.5f * (tp * (tl - lm) + sp * (sl - lm));
    if (colIdx == lbl) hard = -sl;
  };
  for (int i = threadIdx.x; i < n4; i += 256) {
    float4 a = ps[i], b = pt[i];
    term(a.x, b.x, i * 4 + 0);
    term(a.y, b.y, i * 4 + 1);
    term(a.z, b.z, i * 4 + 2);
    term(a.w, b.w, i * 4 + 3);
  }
  #pragma unroll
  for (int off = 32; off > 0; off >>= 1) {
    jsd += __shfl_xor(jsd, off);
    hard += __shfl_xor(hard, off);
  }
  __shared__ float sj[4], sh[4];
  const int w = threadIdx.x >> 6;
  if ((threadIdx.x & 63) == 0) { sj[w] = jsd; sh[w] = hard; }
  __syncthreads();
  if (threadIdx.x == 0) {
    atomicAdd(&acc[0], sh[0] + sh[1] + sh[2] + sh[3]);
    atomicAdd(&acc[1], sj[0] + sj[1] + sj[2] + sj[3]);
  }
}

__global__ void finalize_loss(const float* __restrict__ acc, float* __restrict__ out,
                              float invn) {
  out[0] = 0.5f * acc[0] * invn + 0.5f * acc[1] * invn;
}

// -----------------------------------------------------------------------------
extern "C" void kernel_launch(void* const* d_in, const int* in_sizes, int n_in,
                              void* d_out, int out_size, void* d_ws, size_t ws_size,
                              hipStream_t stream) {
  const float* sIn = (const float*)d_in[0];
  const float* sW  = (const float*)d_in[1];
  const float* tIn = (const float*)d_in[2];
  const float* tW  = (const float*)d_in[3];
  const int*   lbl = (const int*)d_in[4];

  const int N  = in_sizes[4];          // 2048 tokens
  const int HS = in_sizes[0] / N;      // 2048
  const int HT = in_sizes[2] / N;      // 4096
  const int V  = in_sizes[1] / HS;     // 32000

  char* ws = (char*)d_ws;
  size_t off = 0;
  auto alloc = [&](size_t b) { size_t p = off; off = (off + b + 255) & ~(size_t)255; return p; };

  const size_t o_sInB = alloc((size_t)N * HS * 2);
  const size_t o_tInB = alloc((size_t)N * HT * 2);
  const size_t o_sLse = alloc((size_t)N * 4);
  const size_t o_tLse = alloc((size_t)N * 4);
  const size_t o_acc  = alloc(256);

  const size_t weightBytes = (size_t)V * HS * 2 + (size_t)V * HT * 2 + 512;
  const size_t minLogits   = 2ull * 128 * V * 4 + 512;
  const bool full = (off + weightBytes + minLogits) <= ws_size;
  size_t o_sWB = 0, o_tWB = 0;
  if (full) {
    o_sWB = alloc((size_t)V * HS * 2);
    o_tWB = alloc((size_t)V * HT * 2);
  }

  // largest power-of-two row chunk (multiple of 128, divides N) that fits
  size_t avail = ws_size > off ? ws_size - off : 0;
  int Rfit = (int)(avail / (2ull * V * 4));
  int R = 128;
  while (R * 2 <= Rfit && R * 2 <= N) R *= 2;
  const size_t o_sL = alloc((size_t)R * V * 4);
  const size_t o_tL = alloc((size_t)R * V * 4);

  hipMemsetAsync(ws + o_acc, 0, 8, stream);

  if (full) {
    auto cvt = [&](const float* src, size_t dstOff, size_t n) {
      long long n4 = (long long)(n / 4);
      int grid = (int)((n4 + 255) / 256);
      if (grid > 2048) grid = 2048;
      cvt_f32_bf16<<<grid, 256, 0, stream>>>(src, (uint2*)(ws + dstOff), n4);
    };
    cvt(sIn, o_sInB, (size_t)N * HS);
    cvt(tIn, o_tInB, (size_t)N * HT);
    cvt(sW,  o_sWB,  (size_t)V * HS);
    cvt(tW,  o_tWB,  (size_t)V * HT);
  }

  for (int r0 = 0; r0 < N; r0 += R) {
    dim3 g(R / 128, V / 128);
    if (full) {
      gemm_bt<0><<<g, 256, 0, stream>>>(ws + o_sInB + (size_t)r0 * HS * 2, ws + o_sWB,
                                        (float*)(ws + o_sL), V, HS);
      gemm_bt<0><<<g, 256, 0, stream>>>(ws + o_tInB + (size_t)r0 * HT * 2, ws + o_tWB,
                                        (float*)(ws + o_tL), V, HT);
    } else {
      gemm_bt<1><<<g, 256, 0, stream>>>(sIn + (size_t)r0 * HS, sW,
                                        (float*)(ws + o_sL), V, HS);
      gemm_bt<1><<<g, 256, 0, stream>>>(tIn + (size_t)r0 * HT, tW,
                                        (float*)(ws + o_tL), V, HT);
    }
    rowstats<<<R, 256, 0, stream>>>((float*)(ws + o_sL), V, (float*)(ws + o_sLse) + r0);
    rowstats<<<R, 256, 0, stream>>>((float*)(ws + o_tL), V, (float*)(ws + o_tLse) + r0);
    jsd_loss<<<R, 256, 0, stream>>>((float*)(ws + o_sL), (float*)(ws + o_tL), V,
                                    (float*)(ws + o_sLse), (float*)(ws + o_tLse),
                                    lbl, r0, (float*)(ws + o_acc));
  }

  finalize_loss<<<1, 1, 0, stream>>>((float*)(ws + o_acc), (float*)d_out, 1.0f / N);
}

// Round 2
// 1653.377 us; speedup vs baseline: 1.0589x; 1.0589x over previous
//
#include <hip/hip_runtime.h>
#include <stdint.h>

#define AS1C(p) ((const __attribute__((address_space(1))) void*)(p))
#define AS3(p)  ((__attribute__((address_space(3))) void*)(p))

typedef short bf16x8 __attribute__((ext_vector_type(8)));
typedef float f32x4  __attribute__((ext_vector_type(4)));

static __device__ __forceinline__ unsigned pack_bf16_2(float lo, float hi) {
  // two fp32 -> packed bf16x2 (truncation; systematic <0.4% scale error,
  // cancels in softmax/JSD to well below the 2% tolerance)
  return (__float_as_uint(lo) >> 16) | (__float_as_uint(hi) & 0xFFFF0000u);
}

// ---------------- fp32 -> bf16 convert (vectorized, grid-stride) -------------
__global__ __launch_bounds__(256) void cvt_f32_bf16(const float* __restrict__ in,
                                                    uint2* __restrict__ out,
                                                    long long n4) {
  long long i = (long long)blockIdx.x * blockDim.x + threadIdx.x;
  long long stride = (long long)gridDim.x * blockDim.x;
  const float4* in4 = (const float4*)in;
  for (; i < n4; i += stride) {
    float4 v = in4[i];
    uint2 o;
    o.x = pack_bf16_2(v.x, v.y);
    o.y = pack_bf16_2(v.z, v.w);
    out[i] = o;
  }
}

// ---------------- GEMM: C[M][N] = A[M][K] · B[N][K]^T ------------------------
// 128x128 tile, BK=64, 4 waves (2x2), 16x16x32 bf16 MFMA.
// T2 LDS swizzle: logical (row, k_short) stored at k_short ^ ((row&7)<<3).
//   MODE 0: LDS dest linear (global_load_lds requirement); the per-lane GLOBAL
//           source k is pre-swizzled (rule #21: source perm == read perm).
//   MODE 1: fp32 inputs, reg-staged bf16 convert, swizzle applied on ds_write.
template<int MODE>
__global__ __launch_bounds__(256) void gemm_bt(const void* __restrict__ Av,
                                               const void* __restrict__ Bv,
                                               float* __restrict__ C,
                                               int N, int K) {
  __shared__ __align__(16) short sA[128 * 64];
  __shared__ __align__(16) short sB[128 * 64];
  const int t = threadIdx.x;
  const int lane = t & 63;
  const int wv = t >> 6;
  const int wm = wv >> 1, wn = wv & 1;
  const int rowA0 = blockIdx.x * 128;   // M-tile
  const int rowB0 = blockIdx.y * 128;   // N-tile (weight rows)

  f32x4 acc[4][4] = {};

  for (int k0 = 0; k0 < K; k0 += 64) {
    if constexpr (MODE == 0) {
      const short* A = (const short*)Av;
      const short* B = (const short*)Bv;
      #pragma unroll
      for (int i = 0; i < 4; ++i) {
        const int c = wv * 4 + i;             // wave-uniform LDS chunk (1024B)
        const int row = c * 8 + (lane >> 3);  // per-lane global row
        // pre-swizzled source k: lane's linear LDS slot (row, (lane&7)*8)
        // must hold logical k = phys ^ ((row&7)<<3); row&7 == lane>>3 here.
        const int kk = ((lane & 7) ^ (lane >> 3)) * 8;
        __builtin_amdgcn_global_load_lds(AS1C(A + (size_t)(rowA0 + row) * K + k0 + kk),
                                         AS3(sA + c * 512), 16, 0, 0);
        __builtin_amdgcn_global_load_lds(AS1C(B + (size_t)(rowB0 + row) * K + k0 + kk),
                                         AS3(sB + c * 512), 16, 0, 0);
      }
      asm volatile("s_waitcnt vmcnt(0)" ::: "memory");
    } else {
      const float* A = (const float*)Av;
      const float* B = (const float*)Bv;
      #pragma unroll
      for (int i = 0; i < 8; ++i) {
        const int o = i * 1024 + t * 4;       // logical element offset, 128x64 tile
        const int row = o >> 6;
        const int kcol = o & 63;
        const int dst = row * 64 + (kcol ^ ((row & 7) << 3));  // swizzled store
        float4 va = *(const float4*)(A + (size_t)(rowA0 + row) * K + k0 + kcol);
        float4 vb = *(const float4*)(B + (size_t)(rowB0 + row) * K + k0 + kcol);
        uint2 pa, pb;
        pa.x = pack_bf16_2(va.x, va.y); pa.y = pack_bf16_2(va.z, va.w);
        pb.x = pack_bf16_2(vb.x, vb.y); pb.y = pack_bf16_2(vb.z, vb.w);
        *(uint2*)(sA + dst) = pa;
        *(uint2*)(sB + dst) = pb;
      }
    }
    __syncthreads();
    #pragma unroll
    for (int kk = 0; kk < 2; ++kk) {
      bf16x8 af[4], bfr[4];
      #pragma unroll
      for (int mi = 0; mi < 4; ++mi) {
        const int row = wm * 64 + mi * 16 + (lane & 15);
        const int koff = (kk * 32 + (lane >> 4) * 8) ^ ((row & 7) << 3);
        af[mi] = *(const bf16x8*)&sA[row * 64 + koff];
      }
      #pragma unroll
      for (int ni = 0; ni < 4; ++ni) {
        const int col = wn * 64 + ni * 16 + (lane & 15);
        const int koff = (kk * 32 + (lane >> 4) * 8) ^ ((col & 7) << 3);
        bfr[ni] = *(const bf16x8*)&sB[col * 64 + koff];
      }
      #pragma unroll
      for (int mi = 0; mi < 4; ++mi)
        #pragma unroll
        for (int ni = 0; ni < 4; ++ni)
          acc[mi][ni] = __builtin_amdgcn_mfma_f32_16x16x32_bf16(af[mi], bfr[ni],
                                                                acc[mi][ni], 0, 0, 0);
    }
    __syncthreads();
  }

  // Epilogue: C/D layout col=lane&15, row=(lane>>4)*4+r (m89-verified)
  #pragma unroll
  for (int mi = 0; mi < 4; ++mi) {
    #pragma unroll
    for (int ni = 0; ni < 4; ++ni) {
      const int col = rowB0 + wn * 64 + ni * 16 + (lane & 15);
      const int rowb = rowA0 + wm * 64 + mi * 16 + ((lane >> 4) * 4);
      #pragma unroll
      for (int r = 0; r < 4; ++r)
        C[(size_t)(rowb + r) * N + col] = acc[mi][ni][r];
    }
  }
}

// ---------------- per-row online max + log-sum-exp ---------------------------
__global__ __launch_bounds__(256) void rowstats(const float* __restrict__ L, int V,
                                                float* __restrict__ lseOut) {
  const int row = blockIdx.x;
  const float4* p = (const float4*)(L + (size_t)row * V);
  const int n4 = V >> 2;
  float m = -1e30f, s = 0.f;
  for (int i = threadIdx.x; i < n4; i += 256) {
    float4 v = p[i];
    float lm = fmaxf(fmaxf(v.x, v.y), fmaxf(v.z, v.w));
    if (lm > m) { s *= __expf(m - lm); m = lm; }
    s += __expf(v.x - m) + __expf(v.y - m) + __expf(v.z - m) + __expf(v.w - m);
  }
  #pragma unroll
  for (int off = 32; off > 0; off >>= 1) {
    float mo = __shfl_xor(m, off);
    float so = __shfl_xor(s, off);
    float mn = fmaxf(m, mo);
    s = s * __expf(m - mn) + so * __expf(mo - mn);
    m = mn;
  }
  __shared__ float sm[4], ss[4];
  const int w = threadIdx.x >> 6;
  if ((threadIdx.x & 63) == 0) { sm[w] = m; ss[w] = s; }
  __syncthreads();
  if (threadIdx.x == 0) {
    float M = sm[0], S = ss[0];
    for (int i = 1; i < 4; ++i) {
      float mn = fmaxf(M, sm[i]);
      S = S * __expf(M - mn) + ss[i] * __expf(sm[i] - mn);
      M = mn;
    }
    lseOut[row] = M + __logf(S);
  }
}

// ---------------- fused JSD + hard NLL over one row --------------------------
__global__ __launch_bounds__(256) void jsd_loss(const float* __restrict__ SL,
                                                const float* __restrict__ TL, int V,
                                                const float* __restrict__ sLse,
                                                const float* __restrict__ tLse,
                                                const int* __restrict__ labels,
                                                int rowOff, float* __restrict__ acc) {
  const int row = blockIdx.x;
  const float4* ps = (const float4*)(SL + (size_t)row * V);
  const float4* pt = (const float4*)(TL + (size_t)row * V);
  const float slse = sLse[rowOff + row];
  const float tlse = tLse[rowOff + row];
  const int lbl = labels[rowOff + row];   // -100 never matches a column -> auto-ignored
  float jsd = 0.f, hard = 0.f;
  const int n4 = V >> 2;
  auto term = [&](float sv, float tv, int colIdx) {
    float sl = sv - slse;
    float tl = tv - tlse;
    float sp = __expf(sl), tp = __expf(tl);
    float lm = __logf(0.5f * (sp + tp));
    jsd += 0.5f * (tp * (tl - lm) + sp * (sl - lm));
    if (colIdx == lbl) hard = -sl;
  };
  for (int i = threadIdx.x; i < n4; i += 256) {
    float4 a = ps[i], b = pt[i];
    term(a.x, b.x, i * 4 + 0);
    term(a.y, b.y, i * 4 + 1);
    term(a.z, b.z, i * 4 + 2);
    term(a.w, b.w, i * 4 + 3);
  }
  #pragma unroll
  for (int off = 32; off > 0; off >>= 1) {
    jsd += __shfl_xor(jsd, off);
    hard += __shfl_xor(hard, off);
  }
  __shared__ float sj[4], sh[4];
  const int w = threadIdx.x >> 6;
  if ((threadIdx.x & 63) == 0) { sj[w] = jsd; sh[w] = hard; }
  __syncthreads();
  if (threadIdx.x == 0) {
    atomicAdd(&acc[0], sh[0] + sh[1] + sh[2] + sh[3]);
    atomicAdd(&acc[1], sj[0] + sj[1] + sj[2] + sj[3]);
  }
}

__global__ void finalize_loss(const float* __restrict__ acc, float* __restrict__ out,
                              float invn) {
  out[0] = 0.5f * acc[0] * invn + 0.5f * acc[1] * invn;
}

// -----------------------------------------------------------------------------
extern "C" void kernel_launch(void* const* d_in, const int* in_sizes, int n_in,
                              void* d_out, int out_size, void* d_ws, size_t ws_size,
                              hipStream_t stream) {
  const float* sIn = (const float*)d_in[0];
  const float* sW  = (const float*)d_in[1];
  const float* tIn = (const float*)d_in[2];
  const float* tW  = (const float*)d_in[3];
  const int*   lbl = (const int*)d_in[4];

  const int N  = in_sizes[4];          // 2048 tokens
  const int HS = in_sizes[0] / N;      // 2048
  const int HT = in_sizes[2] / N;      // 4096
  const int V  = in_sizes[1] / HS;     // 32000

  char* ws = (char*)d_ws;
  size_t off = 0;
  auto alloc = [&](size_t b) { size_t p = off; off = (off + b + 255) & ~(size_t)255; return p; };

  const size_t o_sInB = alloc((size_t)N * HS * 2);
  const size_t o_tInB = alloc((size_t)N * HT * 2);
  const size_t o_sLse = alloc((size_t)N * 4);
  const size_t o_tLse = alloc((size_t)N * 4);
  const size_t o_acc  = alloc(256);

  const size_t weightBytes = (size_t)V * HS * 2 + (size_t)V * HT * 2 + 512;
  const size_t minLogits   = 2ull * 128 * V * 4 + 512;
  const bool full = (off + weightBytes + minLogits) <= ws_size;
  size_t o_sWB = 0, o_tWB = 0;
  if (full) {
    o_sWB = alloc((size_t)V * HS * 2);
    o_tWB = alloc((size_t)V * HT * 2);
  }

  // largest power-of-two row chunk (multiple of 128, divides N) that fits
  size_t avail = ws_size > off ? ws_size - off : 0;
  int Rfit = (int)(avail / (2ull * V * 4));
  int R = 128;
  while (R * 2 <= Rfit && R * 2 <= N) R *= 2;
  const size_t o_sL = alloc((size_t)R * V * 4);
  const size_t o_tL = alloc((size_t)R * V * 4);

  hipMemsetAsync(ws + o_acc, 0, 8, stream);

  if (full) {
    auto cvt = [&](const float* src, size_t dstOff, size_t n) {
      long long n4 = (long long)(n / 4);
      int grid = (int)((n4 + 255) / 256);
      if (grid > 2048) grid = 2048;
      cvt_f32_bf16<<<grid, 256, 0, stream>>>(src, (uint2*)(ws + dstOff), n4);
    };
    cvt(sIn, o_sInB, (size_t)N * HS);
    cvt(tIn, o_tInB, (size_t)N * HT);
    cvt(sW,  o_sWB,  (size_t)V * HS);
    cvt(tW,  o_tWB,  (size_t)V * HT);
  }

  for (int r0 = 0; r0 < N; r0 += R) {
    dim3 g(R / 128, V / 128);
    if (full) {
      gemm_bt<0><<<g, 256, 0, stream>>>(ws + o_sInB + (size_t)r0 * HS * 2, ws + o_sWB,
                                        (float*)(ws + o_sL), V, HS);
      gemm_bt<0><<<g, 256, 0, stream>>>(ws + o_tInB + (size_t)r0 * HT * 2, ws + o_tWB,
                                        (float*)(ws + o_tL), V, HT);
    } else {
      gemm_bt<1><<<g, 256, 0, stream>>>(sIn + (size_t)r0 * HS, sW,
                                        (float*)(ws + o_sL), V, HS);
      gemm_bt<1><<<g, 256, 0, stream>>>(tIn + (size_t)r0 * HT, tW,
                                        (float*)(ws + o_tL), V, HT);
    }
    rowstats<<<R, 256, 0, stream>>>((float*)(ws + o_sL), V, (float*)(ws + o_sLse) + r0);
    rowstats<<<R, 256, 0, stream>>>((float*)(ws + o_tL), V, (float*)(ws + o_tLse) + r0);
    jsd_loss<<<R, 256, 0, stream>>>((float*)(ws + o_sL), (float*)(ws + o_tL), V,
                                    (float*)(ws + o_sLse), (float*)(ws + o_tLse),
                                    lbl, r0, (float*)(ws + o_acc));
  }

  finalize_loss<<<1, 1, 0, stream>>>((float*)(ws + o_acc), (float*)d_out, 1.0f / N);
}

// Round 3
// 1344.118 us; speedup vs baseline: 1.3025x; 1.2301x over previous
//
#include <hip/hip_runtime.h>
#include <stdint.h>

#define AS1C(p) ((const __attribute__((address_space(1))) void*)(p))
#define AS3(p)  ((__attribute__((address_space(3))) void*)(p))

typedef short bf16x8 __attribute__((ext_vector_type(8)));
typedef float f32x4  __attribute__((ext_vector_type(4)));

static __device__ __forceinline__ unsigned pack_bf16_2(float lo, float hi) {
  return (__float_as_uint(lo) >> 16) | (__float_as_uint(hi) & 0xFFFF0000u);
}

// ---------------- fp32 -> bf16 convert (vectorized, grid-stride) -------------
__global__ __launch_bounds__(256) void cvt_f32_bf16(const float* __restrict__ in,
                                                    uint2* __restrict__ out,
                                                    long long n4) {
  long long i = (long long)blockIdx.x * blockDim.x + threadIdx.x;
  long long stride = (long long)gridDim.x * blockDim.x;
  const float4* in4 = (const float4*)in;
  for (; i < n4; i += stride) {
    float4 v = in4[i];
    uint2 o;
    o.x = pack_bf16_2(v.x, v.y);
    o.y = pack_bf16_2(v.z, v.w);
    out[i] = o;
  }
}

// ---------------- 256x256 8-phase GEMM: C[M][N] = A[M][K] · B[N][K]^T --------
// 8 waves (2M x 4N), per-wave 128x64 output. BK=64, 2 K-tiles double-buffered.
// LDS: sA/sB each [2 buf][2 half][128 rows][64 k] bf16 = 64 KiB -> 128 KiB tot.
// T2 swizzle: logical (r,k8) stored at k8 ^ (r&7) (granule = 8 shorts);
//   global_load_lds keeps LDS linear, global source k is pre-swizzled.
// T3/T4: one half-tile staged per phase, boundary s_waitcnt vmcnt(2) (counted,
//   never 0 in steady state), RAW s_barrier only (no __syncthreads drain).
// T5: setprio(1) around each 16-MFMA cluster.

static __device__ __forceinline__ void stage2(const short* __restrict__ G, int K,
                                              int grow0, int k0,
                                              short* lds, int tid) {
  const int rl = tid >> 3;                       // 0..63 local row
  const int ks = ((tid & 7) ^ (rl & 7)) << 3;    // pre-swizzled source k (shorts)
  const short* src = G + (size_t)(grow0 + rl) * K + k0 + ks;
  short* dst = lds + (tid >> 6) * 512;           // wave-uniform base (+lane*16B HW)
  __builtin_amdgcn_global_load_lds(AS1C(src), AS3(dst), 16, 0, 0);
  __builtin_amdgcn_global_load_lds(AS1C(src + (size_t)64 * K), AS3(dst + 4096), 16, 0, 0);
}

#define MFMA16(IM0, JN0)                                                        \
  __builtin_amdgcn_s_setprio(1);                                                \
  _Pragma("unroll")                                                             \
  for (int mi = 0; mi < 4; ++mi) {                                              \
    _Pragma("unroll")                                                           \
    for (int nj = 0; nj < 2; ++nj) {                                            \
      acc[(IM0) + mi][(JN0) + nj] = __builtin_amdgcn_mfma_f32_16x16x32_bf16(    \
          a_[mi][0], b_[(JN0) + nj][0], acc[(IM0) + mi][(JN0) + nj], 0, 0, 0);  \
      acc[(IM0) + mi][(JN0) + nj] = __builtin_amdgcn_mfma_f32_16x16x32_bf16(    \
          a_[mi][1], b_[(JN0) + nj][1], acc[(IM0) + mi][(JN0) + nj], 0, 0, 0);  \
    }                                                                           \
  }                                                                             \
  __builtin_amdgcn_s_setprio(0);

__global__ __launch_bounds__(512, 2) void gemm8p(const short* __restrict__ A,
                                                 const short* __restrict__ B,
                                                 float* __restrict__ C,
                                                 int N, int K, int mshift, int NT) {
  __shared__ __align__(16) short sA[4 * 8192];
  __shared__ __align__(16) short sB[4 * 8192];

  const int tid = threadIdx.x;
  const int lane = tid & 63;
  const int wv = tid >> 6;
  const int wm = wv >> 2;        // 0..1 : which 128-row half of A this wave owns
  const int wn = wv & 3;         // 0..3 : which 64-col slice of B

  // bijective XCD-aware block swizzle (m204 variant)
  const int nwg = gridDim.x;
  const int orig = blockIdx.x;
  const int q = nwg >> 3, r = nwg & 7;
  const int xcd = orig & 7;
  const int wg = (xcd < r ? xcd * (q + 1) : r * (q + 1) + (xcd - r) * q) + (orig >> 3);
  const int bm = wg & ((1 << mshift) - 1);
  const int bn = wg >> mshift;

  const int mrow0 = bm << 8;
  const int nrow0 = bn << 8;

  const int lr = lane & 15;
  const int koff0 = (((lane >> 4) << 3) ^ ((lane & 7) << 3));
  const int koff1 = ((32 + ((lane >> 4) << 3)) ^ ((lane & 7) << 3));

  f32x4 acc[8][4] = {};
  bf16x8 a_[4][2], b_[4][2];

  // ---- prologue: tile0 fully + tile1 A-half0; wait all but last 2 loads
  stage2(A, K, mrow0,       0, sA + 0 * 8192, tid);
  stage2(A, K, mrow0 + 128, 0, sA + 1 * 8192, tid);
  stage2(B, K, nrow0,       0, sB + 0 * 8192, tid);
  stage2(B, K, nrow0 + 128, 0, sB + 1 * 8192, tid);
  if (NT > 1) {
    stage2(A, K, mrow0, 64, sA + 2 * 8192, tid);
    asm volatile("s_waitcnt vmcnt(2)" ::: "memory");
  } else {
    asm volatile("s_waitcnt vmcnt(0)" ::: "memory");
  }
  __builtin_amdgcn_s_barrier();

  for (int t = 0; t < NT; ++t) {
    const int c = t & 1;
    const short* aB = sA + (c * 2 + wm) * 8192;
    const short* bB = sB + (c * 2 + (wn >> 1)) * 8192;
    short* nxA = sA + ((c ^ 1) * 2) * 8192;
    short* nxB = sB + ((c ^ 1) * 2) * 8192;
    const int k1 = (t + 1) * 64;
    const int bcol = (wn & 1) * 64;

    // ---- phase a: read A[qm0] + B[n0,n1]; stage next A-half1; MFMA quad(0,0)
    #pragma unroll
    for (int mi = 0; mi < 4; ++mi) {
      a_[mi][0] = *(const bf16x8*)&aB[(mi * 16 + lr) * 64 + koff0];
      a_[mi][1] = *(const bf16x8*)&aB[(mi * 16 + lr) * 64 + koff1];
    }
    #pragma unroll
    for (int nj = 0; nj < 2; ++nj) {
      const int cb = (bcol + nj * 16 + lr) * 64;
      b_[nj][0] = *(const bf16x8*)&bB[cb + koff0];
      b_[nj][1] = *(const bf16x8*)&bB[cb + koff1];
    }
    if (t + 1 < NT) stage2(A, K, mrow0 + 128, k1, nxA + 8192, tid);
    __builtin_amdgcn_s_barrier();
    MFMA16(0, 0)
    __builtin_amdgcn_s_barrier();

    // ---- phase b: read B[n2,n3]; stage next B-half0; MFMA quad(0,1)
    #pragma unroll
    for (int nj = 0; nj < 2; ++nj) {
      const int cb = (bcol + (nj + 2) * 16 + lr) * 64;
      b_[nj + 2][0] = *(const bf16x8*)&bB[cb + koff0];
      b_[nj + 2][1] = *(const bf16x8*)&bB[cb + koff1];
    }
    if (t + 1 < NT) stage2(B, K, nrow0, k1, nxB, tid);
    __builtin_amdgcn_s_barrier();
    MFMA16(0, 2)
    __builtin_amdgcn_s_barrier();

    // ---- phase c: read A[qm1]; stage next B-half1; MFMA quad(1,1)
    #pragma unroll
    for (int mi = 0; mi < 4; ++mi) {
      a_[mi][0] = *(const bf16x8*)&aB[(64 + mi * 16 + lr) * 64 + koff0];
      a_[mi][1] = *(const bf16x8*)&aB[(64 + mi * 16 + lr) * 64 + koff1];
    }
    if (t + 1 < NT) stage2(B, K, nrow0 + 128, k1, nxB + 8192, tid);
    __builtin_amdgcn_s_barrier();
    MFMA16(4, 2)
    __builtin_amdgcn_s_barrier();

    // ---- phase d: stage tile t+2 A-half0 (into current buf); MFMA quad(1,0);
    //      counted boundary wait: all of tile t+1 landed, t+2's 2 loads fly.
    if (t + 2 < NT) stage2(A, K, mrow0, (t + 2) * 64, sA + c * 2 * 8192, tid);
    __builtin_amdgcn_s_barrier();
    MFMA16(4, 0)
    if (t + 2 < NT) asm volatile("s_waitcnt vmcnt(2)" ::: "memory");
    else            asm volatile("s_waitcnt vmcnt(0)" ::: "memory");
    __builtin_amdgcn_s_barrier();
  }

  // ---- epilogue: C/D layout col=lane&15, row=(lane>>4)*4+r
  #pragma unroll
  for (int im = 0; im < 8; ++im) {
    const int row = mrow0 + wm * 128 + im * 16 + ((lane >> 4) << 2);
    #pragma unroll
    for (int ni = 0; ni < 4; ++ni) {
      const int col = nrow0 + wn * 64 + ni * 16 + lr;
      #pragma unroll
      for (int rr = 0; rr < 4; ++rr)
        C[(size_t)(row + rr) * N + col] = acc[im][ni][rr];
    }
  }
}

// ---------------- 128x128 fallback GEMM (fp32 in, reg-staged bf16) -----------
__global__ __launch_bounds__(256) void gemm_lean(const float* __restrict__ A,
                                                 const float* __restrict__ B,
                                                 float* __restrict__ C,
                                                 int N, int K) {
  __shared__ __align__(16) short sA[128 * 64];
  __shared__ __align__(16) short sB[128 * 64];
  const int t = threadIdx.x;
  const int lane = t & 63;
  const int wv = t >> 6;
  const int wm = wv >> 1, wn = wv & 1;
  const int rowA0 = blockIdx.x * 128;
  const int rowB0 = blockIdx.y * 128;

  f32x4 acc[4][4] = {};

  for (int k0 = 0; k0 < K; k0 += 64) {
    #pragma unroll
    for (int i = 0; i < 8; ++i) {
      const int o = i * 1024 + t * 4;
      const int row = o >> 6;
      const int kcol = o & 63;
      const int dst = row * 64 + (kcol ^ ((row & 7) << 3));
      float4 va = *(const float4*)(A + (size_t)(rowA0 + row) * K + k0 + kcol);
      float4 vb = *(const float4*)(B + (size_t)(rowB0 + row) * K + k0 + kcol);
      uint2 pa, pb;
      pa.x = pack_bf16_2(va.x, va.y); pa.y = pack_bf16_2(va.z, va.w);
      pb.x = pack_bf16_2(vb.x, vb.y); pb.y = pack_bf16_2(vb.z, vb.w);
      *(uint2*)(sA + dst) = pa;
      *(uint2*)(sB + dst) = pb;
    }
    __syncthreads();
    #pragma unroll
    for (int kk = 0; kk < 2; ++kk) {
      bf16x8 af[4], bfr[4];
      #pragma unroll
      for (int mi = 0; mi < 4; ++mi) {
        const int row = wm * 64 + mi * 16 + (lane & 15);
        const int koff = (kk * 32 + (lane >> 4) * 8) ^ ((row & 7) << 3);
        af[mi] = *(const bf16x8*)&sA[row * 64 + koff];
      }
      #pragma unroll
      for (int ni = 0; ni < 4; ++ni) {
        const int col = wn * 64 + ni * 16 + (lane & 15);
        const int koff = (kk * 32 + (lane >> 4) * 8) ^ ((col & 7) << 3);
        bfr[ni] = *(const bf16x8*)&sB[col * 64 + koff];
      }
      #pragma unroll
      for (int mi = 0; mi < 4; ++mi)
        #pragma unroll
        for (int ni = 0; ni < 4; ++ni)
          acc[mi][ni] = __builtin_amdgcn_mfma_f32_16x16x32_bf16(af[mi], bfr[ni],
                                                                acc[mi][ni], 0, 0, 0);
    }
    __syncthreads();
  }

  #pragma unroll
  for (int mi = 0; mi < 4; ++mi)
    #pragma unroll
    for (int ni = 0; ni < 4; ++ni) {
      const int col = rowB0 + wn * 64 + ni * 16 + (lane & 15);
      const int rowb = rowA0 + wm * 64 + mi * 16 + ((lane >> 4) * 4);
      #pragma unroll
      for (int r = 0; r < 4; ++r)
        C[(size_t)(rowb + r) * N + col] = acc[mi][ni][r];
    }
}

// ---------------- per-row online max + log-sum-exp ---------------------------
__global__ __launch_bounds__(256) void rowstats(const float* __restrict__ L, int V,
                                                float* __restrict__ lseOut) {
  const int row = blockIdx.x;
  const float4* p = (const float4*)(L + (size_t)row * V);
  const int n4 = V >> 2;
  float m = -1e30f, s = 0.f;
  for (int i = threadIdx.x; i < n4; i += 256) {
    float4 v = p[i];
    float lm = fmaxf(fmaxf(v.x, v.y), fmaxf(v.z, v.w));
    if (lm > m) { s *= __expf(m - lm); m = lm; }
    s += __expf(v.x - m) + __expf(v.y - m) + __expf(v.z - m) + __expf(v.w - m);
  }
  #pragma unroll
  for (int off = 32; off > 0; off >>= 1) {
    float mo = __shfl_xor(m, off);
    float so = __shfl_xor(s, off);
    float mn = fmaxf(m, mo);
    s = s * __expf(m - mn) + so * __expf(mo - mn);
    m = mn;
  }
  __shared__ float sm[4], ss[4];
  const int w = threadIdx.x >> 6;
  if ((threadIdx.x & 63) == 0) { sm[w] = m; ss[w] = s; }
  __syncthreads();
  if (threadIdx.x == 0) {
    float M = sm[0], S = ss[0];
    for (int i = 1; i < 4; ++i) {
      float mn = fmaxf(M, sm[i]);
      S = S * __expf(M - mn) + ss[i] * __expf(sm[i] - mn);
      M = mn;
    }
    lseOut[row] = M + __logf(S);
  }
}

// ---------------- fused JSD + hard NLL over one row --------------------------
__global__ __launch_bounds__(256) void jsd_loss(const float* __restrict__ SL,
                                                const float* __restrict__ TL, int V,
                                                const float* __restrict__ sLse,
                                                const float* __restrict__ tLse,
                                                const int* __restrict__ labels,
                                                int rowOff, float* __restrict__ acc) {
  const int row = blockIdx.x;
  const float4* ps = (const float4*)(SL + (size_t)row * V);
  const float4* pt = (const float4*)(TL + (size_t)row * V);
  const float slse = sLse[rowOff + row];
  const float tlse = tLse[rowOff + row];
  const int lbl = labels[rowOff + row];
  float jsd = 0.f, hard = 0.f;
  const int n4 = V >> 2;
  auto term = [&](float sv, float tv, int colIdx) {
    float sl = sv - slse;
    float tl = tv - tlse;
    float sp = __expf(sl), tp = __expf(tl);
    float lm = __logf(0.5f * (sp + tp));
    jsd += 0.5f * (tp * (tl - lm) + sp * (sl - lm));
    if (colIdx == lbl) hard = -sl;
  };
  for (int i = threadIdx.x; i < n4; i += 256) {
    float4 a = ps[i], b = pt[i];
    term(a.x, b.x, i * 4 + 0);
    term(a.y, b.y, i * 4 + 1);
    term(a.z, b.z, i * 4 + 2);
    term(a.w, b.w, i * 4 + 3);
  }
  #pragma unroll
  for (int off = 32; off > 0; off >>= 1) {
    jsd += __shfl_xor(jsd, off);
    hard += __shfl_xor(hard, off);
  }
  __shared__ float sj[4], sh[4];
  const int w = threadIdx.x >> 6;
  if ((threadIdx.x & 63) == 0) { sj[w] = jsd; sh[w] = hard; }
  __syncthreads();
  if (threadIdx.x == 0) {
    atomicAdd(&acc[0], sh[0] + sh[1] + sh[2] + sh[3]);
    atomicAdd(&acc[1], sj[0] + sj[1] + sj[2] + sj[3]);
  }
}

__global__ void finalize_loss(const float* __restrict__ acc, float* __restrict__ out,
                              float invn) {
  out[0] = 0.5f * acc[0] * invn + 0.5f * acc[1] * invn;
}

// -----------------------------------------------------------------------------
extern "C" void kernel_launch(void* const* d_in, const int* in_sizes, int n_in,
                              void* d_out, int out_size, void* d_ws, size_t ws_size,
                              hipStream_t stream) {
  const float* sIn = (const float*)d_in[0];
  const float* sW  = (const float*)d_in[1];
  const float* tIn = (const float*)d_in[2];
  const float* tW  = (const float*)d_in[3];
  const int*   lbl = (const int*)d_in[4];

  const int N  = in_sizes[4];          // 2048 tokens
  const int HS = in_sizes[0] / N;      // 2048
  const int HT = in_sizes[2] / N;      // 4096
  const int V  = in_sizes[1] / HS;     // 32000

  char* ws = (char*)d_ws;
  size_t off = 0;
  auto alloc = [&](size_t b) { size_t p = off; off = (off + b + 255) & ~(size_t)255; return p; };

  const size_t o_sInB = alloc((size_t)N * HS * 2);
  const size_t o_tInB = alloc((size_t)N * HT * 2);
  const size_t o_sLse = alloc((size_t)N * 4);
  const size_t o_tLse = alloc((size_t)N * 4);
  const size_t o_acc  = alloc(256);

  const bool shapeOK = (V % 256 == 0) && (HS % 64 == 0) && (HT % 64 == 0) && (N % 256 == 0);
  const size_t weightBytes = (size_t)V * HS * 2 + (size_t)V * HT * 2 + 512;
  const size_t minLogits   = 2ull * 256 * V * 4 + 512;
  const bool full = shapeOK && (off + weightBytes + minLogits) <= ws_size;
  size_t o_sWB = 0, o_tWB = 0;
  if (full) {
    o_sWB = alloc((size_t)V * HS * 2);
    o_tWB = alloc((size_t)V * HT * 2);
  }

  // largest power-of-two row chunk that fits (min 256 full / 128 lean)
  size_t avail = ws_size > off ? ws_size - off : 0;
  int Rfit = (int)(avail / (2ull * V * 4));
  int R = full ? 256 : 128;
  while (R * 2 <= Rfit && R * 2 <= N) R *= 2;
  const size_t o_sL = alloc((size_t)R * V * 4);
  const size_t o_tL = alloc((size_t)R * V * 4);

  hipMemsetAsync(ws + o_acc, 0, 8, stream);

  if (full) {
    auto cvt = [&](const float* src, size_t dstOff, size_t n) {
      long long n4 = (long long)(n / 4);
      int grid = (int)((n4 + 255) / 256);
      if (grid > 2048) grid = 2048;
      cvt_f32_bf16<<<grid, 256, 0, stream>>>(src, (uint2*)(ws + dstOff), n4);
    };
    cvt(sIn, o_sInB, (size_t)N * HS);
    cvt(tIn, o_tInB, (size_t)N * HT);
    cvt(sW,  o_sWB,  (size_t)V * HS);
    cvt(tW,  o_tWB,  (size_t)V * HT);
  }

  const int Mt = R / 256;
  int mshift = 0;
  while ((1 << mshift) < Mt) ++mshift;

  for (int r0 = 0; r0 < N; r0 += R) {
    if (full) {
      gemm8p<<<Mt * (V / 256), 512, 0, stream>>>(
          (const short*)(ws + o_sInB + (size_t)r0 * HS * 2), (const short*)(ws + o_sWB),
          (float*)(ws + o_sL), V, HS, mshift, HS / 64);
      gemm8p<<<Mt * (V / 256), 512, 0, stream>>>(
          (const short*)(ws + o_tInB + (size_t)r0 * HT * 2), (const short*)(ws + o_tWB),
          (float*)(ws + o_tL), V, HT, mshift, HT / 64);
    } else {
      dim3 g(R / 128, V / 128);
      gemm_lean<<<g, 256, 0, stream>>>(sIn + (size_t)r0 * HS, sW,
                                       (float*)(ws + o_sL), V, HS);
      gemm_lean<<<g, 256, 0, stream>>>(tIn + (size_t)r0 * HT, tW,
                                       (float*)(ws + o_tL), V, HT);
    }
    rowstats<<<R, 256, 0, stream>>>((float*)(ws + o_sL), V, (float*)(ws + o_sLse) + r0);
    rowstats<<<R, 256, 0, stream>>>((float*)(ws + o_tL), V, (float*)(ws + o_tLse) + r0);
    jsd_loss<<<R, 256, 0, stream>>>((float*)(ws + o_sL), (float*)(ws + o_tL), V,
                                    (float*)(ws + o_sLse), (float*)(ws + o_tLse),
                                    lbl, r0, (float*)(ws + o_acc));
  }

  finalize_loss<<<1, 1, 0, stream>>>((float*)(ws + o_acc), (float*)d_out, 1.0f / N);
}

// Round 4
// 1154.979 us; speedup vs baseline: 1.5158x; 1.1638x over previous
//
#include <hip/hip_runtime.h>
#include <stdint.h>

#define AS1C(p) ((const __attribute__((address_space(1))) void*)(p))
#define AS3(p)  ((__attribute__((address_space(3))) void*)(p))

typedef short bf16x8 __attribute__((ext_vector_type(8)));
typedef float f32x4  __attribute__((ext_vector_type(4)));
typedef unsigned short u16x8 __attribute__((ext_vector_type(8)));

static __device__ __forceinline__ unsigned pack_bf16_2(float lo, float hi) {
  return (__float_as_uint(lo) >> 16) | (__float_as_uint(hi) & 0xFFFF0000u);
}
static __device__ __forceinline__ unsigned short bf16_rnd(float v) {
  return (unsigned short)((__float_as_uint(v) + 0x8000u) >> 16);  // round-half-up
}
static __device__ __forceinline__ float bf16_f(unsigned short u) {
  return __uint_as_float(((unsigned)u) << 16);
}

// ---------------- fp32 -> bf16 convert (vectorized, grid-stride) -------------
__global__ __launch_bounds__(256) void cvt_f32_bf16(const float* __restrict__ in,
                                                    uint2* __restrict__ out,
                                                    long long n4) {
  long long i = (long long)blockIdx.x * blockDim.x + threadIdx.x;
  long long stride = (long long)gridDim.x * blockDim.x;
  const float4* in4 = (const float4*)in;
  for (; i < n4; i += stride) {
    float4 v = in4[i];
    uint2 o;
    o.x = pack_bf16_2(v.x, v.y);
    o.y = pack_bf16_2(v.z, v.w);
    out[i] = o;
  }
}

// ---------------- 256x256 8-phase GEMM: C = A[M][K] · B[N][K]^T (bf16 out) ---
// 8 waves (2M x 4N). BK=64, 2 K-tiles double-buffered.
// Stagger (max legal lead): B halves fully read by end-phase-b, A by end-c.
//   phase a: stage A0(t+1) | b: A1(t+1) | c: B0(t+2) | d: B1(t+2)
//   boundary: s_waitcnt vmcnt(4)  -- B(t+2)'s 4 loads stay in flight.
// Lead: B0'=5, B1'=4, A0'=3, A1'=2 phases (B is the HBM-streaming operand).

static __device__ __forceinline__ void stage2(const short* __restrict__ G, int K,
                                              int grow0, int k0,
                                              short* lds, int tid) {
  const int rl = tid >> 3;                       // 0..63 local row
  const int ks = ((tid & 7) ^ (rl & 7)) << 3;    // pre-swizzled source k (shorts)
  const short* src = G + (size_t)(grow0 + rl) * K + k0 + ks;
  short* dst = lds + (tid >> 6) * 512;           // wave-uniform base (+lane*16B HW)
  __builtin_amdgcn_global_load_lds(AS1C(src), AS3(dst), 16, 0, 0);
  __builtin_amdgcn_global_load_lds(AS1C(src + (size_t)64 * K), AS3(dst + 4096), 16, 0, 0);
}

#define MFMA16(IM0, JN0)                                                        \
  __builtin_amdgcn_s_setprio(1);                                                \
  _Pragma("unroll")                                                             \
  for (int mi = 0; mi < 4; ++mi) {                                              \
    _Pragma("unroll")                                                           \
    for (int nj = 0; nj < 2; ++nj) {                                            \
      acc[(IM0) + mi][(JN0) + nj] = __builtin_amdgcn_mfma_f32_16x16x32_bf16(    \
          a_[mi][0], b_[(JN0) + nj][0], acc[(IM0) + mi][(JN0) + nj], 0, 0, 0);  \
      acc[(IM0) + mi][(JN0) + nj] = __builtin_amdgcn_mfma_f32_16x16x32_bf16(    \
          a_[mi][1], b_[(JN0) + nj][1], acc[(IM0) + mi][(JN0) + nj], 0, 0, 0);  \
    }                                                                           \
  }                                                                             \
  __builtin_amdgcn_s_setprio(0);

__global__ __launch_bounds__(512, 2) void gemm8p(const short* __restrict__ A,
                                                 const short* __restrict__ B,
                                                 unsigned short* __restrict__ C,
                                                 int N, int K, int mshift, int NT) {
  __shared__ __align__(16) short sA[4 * 8192];
  __shared__ __align__(16) short sB[4 * 8192];

  const int tid = threadIdx.x;
  const int lane = tid & 63;
  const int wv = tid >> 6;
  const int wm = wv >> 2;
  const int wn = wv & 3;

  // bijective XCD-aware block swizzle (m204 variant)
  const int nwg = gridDim.x;
  const int orig = blockIdx.x;
  const int q = nwg >> 3, r = nwg & 7;
  const int xcd = orig & 7;
  const int wg = (xcd < r ? xcd * (q + 1) : r * (q + 1) + (xcd - r) * q) + (orig >> 3);
  const int bm = wg & ((1 << mshift) - 1);
  const int bn = wg >> mshift;

  const int mrow0 = bm << 8;
  const int nrow0 = bn << 8;

  const int lr = lane & 15;
  const int koff0 = (((lane >> 4) << 3) ^ ((lane & 7) << 3));
  const int koff1 = ((32 + ((lane >> 4) << 3)) ^ ((lane & 7) << 3));

  f32x4 acc[8][4] = {};
  bf16x8 a_[4][2], b_[4][2];

  // ---- prologue: tile0 fully + B halves of tile1 (steady-state in-flight)
  stage2(A, K, mrow0,       0, sA + 0 * 8192, tid);
  stage2(A, K, mrow0 + 128, 0, sA + 1 * 8192, tid);
  stage2(B, K, nrow0,       0, sB + 0 * 8192, tid);
  stage2(B, K, nrow0 + 128, 0, sB + 1 * 8192, tid);
  if (NT > 1) {
    stage2(B, K, nrow0,       64, sB + 2 * 8192, tid);
    stage2(B, K, nrow0 + 128, 64, sB + 3 * 8192, tid);
    asm volatile("s_waitcnt vmcnt(4)" ::: "memory");
  } else {
    asm volatile("s_waitcnt vmcnt(0)" ::: "memory");
  }
  __builtin_amdgcn_s_barrier();

  for (int t = 0; t < NT; ++t) {
    const int P = t & 1;
    const short* aB = sA + (P * 2 + wm) * 8192;
    const short* bB = sB + (P * 2 + (wn >> 1)) * 8192;
    const int bcol = (wn & 1) * 64;

    // ---- phase a: read A-half0 frags + B n0,n1; stage A0(t+1); MFMA quad(0,0)
    #pragma unroll
    for (int mi = 0; mi < 4; ++mi) {
      a_[mi][0] = *(const bf16x8*)&aB[(mi * 16 + lr) * 64 + koff0];
      a_[mi][1] = *(const bf16x8*)&aB[(mi * 16 + lr) * 64 + koff1];
    }
    #pragma unroll
    for (int nj = 0; nj < 2; ++nj) {
      const int cb = (bcol + nj * 16 + lr) * 64;
      b_[nj][0] = *(const bf16x8*)&bB[cb + koff0];
      b_[nj][1] = *(const bf16x8*)&bB[cb + koff1];
    }
    if (t + 1 < NT) stage2(A, K, mrow0, (t + 1) * 64, sA + ((P ^ 1) * 2) * 8192, tid);
    __builtin_amdgcn_s_barrier();
    MFMA16(0, 0)
    __builtin_amdgcn_s_barrier();

    // ---- phase b: read B n2,n3; stage A1(t+1); MFMA quad(0,2)
    #pragma unroll
    for (int nj = 0; nj < 2; ++nj) {
      const int cb = (bcol + (nj + 2) * 16 + lr) * 64;
      b_[nj + 2][0] = *(const bf16x8*)&bB[cb + koff0];
      b_[nj + 2][1] = *(const bf16x8*)&bB[cb + koff1];
    }
    if (t + 1 < NT) stage2(A, K, mrow0 + 128, (t + 1) * 64, sA + ((P ^ 1) * 2 + 1) * 8192, tid);
    __builtin_amdgcn_s_barrier();
    MFMA16(0, 2)
    __builtin_amdgcn_s_barrier();

    // ---- phase c: read A-half1 frags; stage B0(t+2) (B buf read done @ end-b)
    #pragma unroll
    for (int mi = 0; mi < 4; ++mi) {
      a_[mi][0] = *(const bf16x8*)&aB[(64 + mi * 16 + lr) * 64 + koff0];
      a_[mi][1] = *(const bf16x8*)&aB[(64 + mi * 16 + lr) * 64 + koff1];
    }
    if (t + 2 < NT) stage2(B, K, nrow0, (t + 2) * 64, sB + (P * 2) * 8192, tid);
    __builtin_amdgcn_s_barrier();
    MFMA16(4, 2)
    __builtin_amdgcn_s_barrier();

    // ---- phase d: stage B1(t+2); MFMA quad(4,0); counted boundary wait
    if (t + 2 < NT) stage2(B, K, nrow0 + 128, (t + 2) * 64, sB + (P * 2 + 1) * 8192, tid);
    __builtin_amdgcn_s_barrier();
    MFMA16(4, 0)
    if (t + 2 < NT) asm volatile("s_waitcnt vmcnt(4)" ::: "memory");
    else            asm volatile("s_waitcnt vmcnt(0)" ::: "memory");
    __builtin_amdgcn_s_barrier();
  }

  // ---- epilogue: C/D layout col=lane&15, row=(lane>>4)*4+r; bf16 store
  #pragma unroll
  for (int im = 0; im < 8; ++im) {
    const int row = mrow0 + wm * 128 + im * 16 + ((lane >> 4) << 2);
    #pragma unroll
    for (int ni = 0; ni < 4; ++ni) {
      const int col = nrow0 + wn * 64 + ni * 16 + lr;
      #pragma unroll
      for (int rr = 0; rr < 4; ++rr)
        C[(size_t)(row + rr) * N + col] = bf16_rnd(acc[im][ni][rr]);
    }
  }
}

// ---------------- 128x128 fallback GEMM (fp32 in, reg-staged bf16) -----------
__global__ __launch_bounds__(256) void gemm_lean(const float* __restrict__ A,
                                                 const float* __restrict__ B,
                                                 unsigned short* __restrict__ C,
                                                 int N, int K) {
  __shared__ __align__(16) short sA[128 * 64];
  __shared__ __align__(16) short sB[128 * 64];
  const int t = threadIdx.x;
  const int lane = t & 63;
  const int wv = t >> 6;
  const int wm = wv >> 1, wn = wv & 1;
  const int rowA0 = blockIdx.x * 128;
  const int rowB0 = blockIdx.y * 128;

  f32x4 acc[4][4] = {};

  for (int k0 = 0; k0 < K; k0 += 64) {
    #pragma unroll
    for (int i = 0; i < 8; ++i) {
      const int o = i * 1024 + t * 4;
      const int row = o >> 6;
      const int kcol = o & 63;
      const int dst = row * 64 + (kcol ^ ((row & 7) << 3));
      float4 va = *(const float4*)(A + (size_t)(rowA0 + row) * K + k0 + kcol);
      float4 vb = *(const float4*)(B + (size_t)(rowB0 + row) * K + k0 + kcol);
      uint2 pa, pb;
      pa.x = pack_bf16_2(va.x, va.y); pa.y = pack_bf16_2(va.z, va.w);
      pb.x = pack_bf16_2(vb.x, vb.y); pb.y = pack_bf16_2(vb.z, vb.w);
      *(uint2*)(sA + dst) = pa;
      *(uint2*)(sB + dst) = pb;
    }
    __syncthreads();
    #pragma unroll
    for (int kk = 0; kk < 2; ++kk) {
      bf16x8 af[4], bfr[4];
      #pragma unroll
      for (int mi = 0; mi < 4; ++mi) {
        const int row = wm * 64 + mi * 16 + (lane & 15);
        const int koff = (kk * 32 + (lane >> 4) * 8) ^ ((row & 7) << 3);
        af[mi] = *(const bf16x8*)&sA[row * 64 + koff];
      }
      #pragma unroll
      for (int ni = 0; ni < 4; ++ni) {
        const int col = wn * 64 + ni * 16 + (lane & 15);
        const int koff = (kk * 32 + (lane >> 4) * 8) ^ ((col & 7) << 3);
        bfr[ni] = *(const bf16x8*)&sB[col * 64 + koff];
      }
      #pragma unroll
      for (int mi = 0; mi < 4; ++mi)
        #pragma unroll
        for (int ni = 0; ni < 4; ++ni)
          acc[mi][ni] = __builtin_amdgcn_mfma_f32_16x16x32_bf16(af[mi], bfr[ni],
                                                                acc[mi][ni], 0, 0, 0);
    }
    __syncthreads();
  }

  #pragma unroll
  for (int mi = 0; mi < 4; ++mi)
    #pragma unroll
    for (int ni = 0; ni < 4; ++ni) {
      const int col = rowB0 + wn * 64 + ni * 16 + (lane & 15);
      const int rowb = rowA0 + wm * 64 + mi * 16 + ((lane >> 4) * 4);
      #pragma unroll
      for (int r = 0; r < 4; ++r)
        C[(size_t)(rowb + r) * N + col] = bf16_rnd(acc[mi][ni][r]);
    }
}

// ---------------- fused lse + JSD + NLL: one block per row, rows in LDS ------
// bf16 logits staged once (125 KB LDS), lse via wave reduce, then JSD pass.
__global__ __launch_bounds__(512) void fused_loss(const unsigned short* __restrict__ SL,
                                                  const unsigned short* __restrict__ TL,
                                                  int V,
                                                  const int* __restrict__ labels,
                                                  int rowOff, float* __restrict__ acc) {
  __shared__ __align__(16) unsigned short bufS[32768];
  __shared__ __align__(16) unsigned short bufT[32768];
  __shared__ float red[4][8];
  const int row = blockIdx.x;
  const int tid = threadIdx.x;
  const u16x8* ps = (const u16x8*)(SL + (size_t)row * V);
  const u16x8* pt = (const u16x8*)(TL + (size_t)row * V);
  const int n8 = V >> 3;

  float ms = -1e30f, ss = 0.f, mt = -1e30f, st = 0.f;
  for (int i = tid; i < n8; i += 512) {
    u16x8 a = ps[i], b = pt[i];
    *(u16x8*)&bufS[i * 8] = a;
    *(u16x8*)&bufT[i * 8] = b;
    float lmS = -1e30f, lmT = -1e30f;
    float fa[8], fb[8];
    #pragma unroll
    for (int j = 0; j < 8; ++j) {
      fa[j] = bf16_f(a[j]); fb[j] = bf16_f(b[j]);
      lmS = fmaxf(lmS, fa[j]); lmT = fmaxf(lmT, fb[j]);
    }
    if (lmS > ms) { ss *= __expf(ms - lmS); ms = lmS; }
    if (lmT > mt) { st *= __expf(mt - lmT); mt = lmT; }
    #pragma unroll
    for (int j = 0; j < 8; ++j) {
      ss += __expf(fa[j] - ms);
      st += __expf(fb[j] - mt);
    }
  }
  #pragma unroll
  for (int off = 32; off > 0; off >>= 1) {
    float mo = __shfl_xor(ms, off), so = __shfl_xor(ss, off);
    float mn = fmaxf(ms, mo);
    ss = ss * __expf(ms - mn) + so * __expf(mo - mn); ms = mn;
    mo = __shfl_xor(mt, off); so = __shfl_xor(st, off);
    mn = fmaxf(mt, mo);
    st = st * __expf(mt - mn) + so * __expf(mo - mn); mt = mn;
  }
  const int w = tid >> 6;
  if ((tid & 63) == 0) { red[0][w] = ms; red[1][w] = ss; red[2][w] = mt; red[3][w] = st; }
  __syncthreads();
  __shared__ float lse2[2];
  if (tid == 0) {
    float M = red[0][0], S = red[1][0];
    for (int i = 1; i < 8; ++i) {
      float mn = fmaxf(M, red[0][i]);
      S = S * __expf(M - mn) + red[1][i] * __expf(red[0][i] - mn); M = mn;
    }
    lse2[0] = M + __logf(S);
    M = red[2][0]; S = red[3][0];
    for (int i = 1; i < 8; ++i) {
      float mn = fmaxf(M, red[2][i]);
      S = S * __expf(M - mn) + red[3][i] * __expf(red[2][i] - mn); M = mn;
    }
    lse2[1] = M + __logf(S);
  }
  __syncthreads();
  const float slse = lse2[0], tlse = lse2[1];
  const int lbl = labels[rowOff + row];   // -100 never matches -> auto-ignored

  float jsd = 0.f, hard = 0.f;
  for (int i = tid; i < n8; i += 512) {
    u16x8 a = *(const u16x8*)&bufS[i * 8];
    u16x8 b = *(const u16x8*)&bufT[i * 8];
    #pragma unroll
    for (int j = 0; j < 8; ++j) {
      float sl = bf16_f(a[j]) - slse;
      float tl = bf16_f(b[j]) - tlse;
      float sp = __expf(sl), tp = __expf(tl);
      float lm = __logf(0.5f * (sp + tp));
      jsd += 0.5f * (tp * (tl - lm) + sp * (sl - lm));
      if (i * 8 + j == lbl) hard = -sl;
    }
  }
  #pragma unroll
  for (int off = 32; off > 0; off >>= 1) {
    jsd += __shfl_xor(jsd, off);
    hard += __shfl_xor(hard, off);
  }
  if ((tid & 63) == 0) { red[0][w] = jsd; red[1][w] = hard; }
  __syncthreads();
  if (tid == 0) {
    float J = 0.f, H = 0.f;
    for (int i = 0; i < 8; ++i) { J += red[0][i]; H += red[1][i]; }
    atomicAdd(&acc[0], H);
    atomicAdd(&acc[1], J);
  }
}

__global__ void finalize_loss(const float* __restrict__ acc, float* __restrict__ out,
                              float invn) {
  out[0] = 0.5f * acc[0] * invn + 0.5f * acc[1] * invn;
}

// -----------------------------------------------------------------------------
extern "C" void kernel_launch(void* const* d_in, const int* in_sizes, int n_in,
                              void* d_out, int out_size, void* d_ws, size_t ws_size,
                              hipStream_t stream) {
  const float* sIn = (const float*)d_in[0];
  const float* sW  = (const float*)d_in[1];
  const float* tIn = (const float*)d_in[2];
  const float* tW  = (const float*)d_in[3];
  const int*   lbl = (const int*)d_in[4];

  const int N  = in_sizes[4];          // 2048 tokens
  const int HS = in_sizes[0] / N;      // 2048
  const int HT = in_sizes[2] / N;      // 4096
  const int V  = in_sizes[1] / HS;     // 32000

  char* ws = (char*)d_ws;
  size_t off = 0;
  auto alloc = [&](size_t b) { size_t p = off; off = (off + b + 255) & ~(size_t)255; return p; };

  const size_t o_sInB = alloc((size_t)N * HS * 2);
  const size_t o_tInB = alloc((size_t)N * HT * 2);
  const size_t o_acc  = alloc(256);

  const bool shapeOK = (V % 256 == 0) && (V <= 32768) && (V % 8 == 0) &&
                       (HS % 64 == 0) && (HT % 64 == 0) && (N % 256 == 0);
  const size_t weightBytes = (size_t)V * HS * 2 + (size_t)V * HT * 2 + 512;
  const size_t minLogits   = 2ull * 256 * V * 2 + 512;
  const bool full = shapeOK && (off + weightBytes + minLogits) <= ws_size;
  size_t o_sWB = 0, o_tWB = 0;
  if (full) {
    o_sWB = alloc((size_t)V * HS * 2);
    o_tWB = alloc((size_t)V * HT * 2);
  }

  // largest power-of-two row chunk that fits (bf16 logits now: 2B/elem)
  size_t avail = ws_size > off ? ws_size - off : 0;
  int Rfit = (int)(avail / (2ull * V * 2));
  int R = full ? 256 : 128;
  while (R * 2 <= Rfit && R * 2 <= N) R *= 2;
  const size_t o_sL = alloc((size_t)R * V * 2);
  const size_t o_tL = alloc((size_t)R * V * 2);

  hipMemsetAsync(ws + o_acc, 0, 8, stream);

  if (full) {
    auto cvt = [&](const float* src, size_t dstOff, size_t n) {
      long long n4 = (long long)(n / 4);
      int grid = (int)((n4 + 255) / 256);
      if (grid > 2048) grid = 2048;
      cvt_f32_bf16<<<grid, 256, 0, stream>>>(src, (uint2*)(ws + dstOff), n4);
    };
    cvt(sIn, o_sInB, (size_t)N * HS);
    cvt(tIn, o_tInB, (size_t)N * HT);
    cvt(sW,  o_sWB,  (size_t)V * HS);
    cvt(tW,  o_tWB,  (size_t)V * HT);
  }

  const int Mt = R / 256;
  int mshift = 0;
  while ((1 << mshift) < Mt) ++mshift;

  for (int r0 = 0; r0 < N; r0 += R) {
    if (full) {
      gemm8p<<<Mt * (V / 256), 512, 0, stream>>>(
          (const short*)(ws + o_sInB + (size_t)r0 * HS * 2), (const short*)(ws + o_sWB),
          (unsigned short*)(ws + o_sL), V, HS, mshift, HS / 64);
      gemm8p<<<Mt * (V / 256), 512, 0, stream>>>(
          (const short*)(ws + o_tInB + (size_t)r0 * HT * 2), (const short*)(ws + o_tWB),
          (unsigned short*)(ws + o_tL), V, HT, mshift, HT / 64);
    } else {
      dim3 g(R / 128, V / 128);
      gemm_lean<<<g, 256, 0, stream>>>(sIn + (size_t)r0 * HS, sW,
                                       (unsigned short*)(ws + o_sL), V, HS);
      gemm_lean<<<g, 256, 0, stream>>>(tIn + (size_t)r0 * HT, tW,
                                       (unsigned short*)(ws + o_tL), V, HT);
    }
    fused_loss<<<R, 512, 0, stream>>>((const unsigned short*)(ws + o_sL),
                                      (const unsigned short*)(ws + o_tL), V,
                                      lbl, r0, (float*)(ws + o_acc));
  }

  finalize_loss<<<1, 1, 0, stream>>>((float*)(ws + o_acc), (float*)d_out, 1.0f / N);
}

// Round 5
// 1052.377 us; speedup vs baseline: 1.6636x; 1.0975x over previous
//
#include <hip/hip_runtime.h>
#include <stdint.h>

#define AS1C(p) ((const __attribute__((address_space(1))) void*)(p))
#define AS3(p)  ((__attribute__((address_space(3))) void*)(p))

typedef short bf16x8 __attribute__((ext_vector_type(8)));
typedef float f32x4  __attribute__((ext_vector_type(4)));
typedef unsigned short u16x8 __attribute__((ext_vector_type(8)));

static __device__ __forceinline__ unsigned pack_bf16_2(float lo, float hi) {
  return (__float_as_uint(lo) >> 16) | (__float_as_uint(hi) & 0xFFFF0000u);
}
static __device__ __forceinline__ unsigned short bf16_rnd(float v) {
  return (unsigned short)((__float_as_uint(v) + 0x8000u) >> 16);
}
static __device__ __forceinline__ float bf16_f(unsigned short u) {
  return __uint_as_float(((unsigned)u) << 16);
}

// ---------------- fp32 -> bf16 convert (inputs only now) ---------------------
__global__ __launch_bounds__(256) void cvt_f32_bf16(const float* __restrict__ in,
                                                    uint2* __restrict__ out,
                                                    long long n4) {
  long long i = (long long)blockIdx.x * blockDim.x + threadIdx.x;
  long long stride = (long long)gridDim.x * blockDim.x;
  const float4* in4 = (const float4*)in;
  for (; i < n4; i += stride) {
    float4 v = in4[i];
    uint2 o;
    o.x = pack_bf16_2(v.x, v.y);
    o.y = pack_bf16_2(v.z, v.w);
    out[i] = o;
  }
}

// ---------------- 256x256 8-phase GEMM, fp32 B fused-convert -----------------
// C[M][N] = A[M][K](bf16) · B[N][K]^T(fp32->bf16 on the fly), bf16 out.
// 8 waves (2M x 4N). BK=64, 2 K-tiles double-buffered, LDS 128 KiB.
// A: global_load_lds with pre-swizzled source (T2 both-sides contract).
// B: T14 reg-staged  — float4 loads issued in phases c,d of tile t-1,
//    packed+ds_write (swizzled) in phases c,d of tile t, read in tile t+1.
// Boundary: s_waitcnt vmcnt(8) lgkmcnt(0) — B(t+2)'s 8 loads stay in flight.

static __device__ __forceinline__ void stage2(const short* __restrict__ G, int K,
                                              int grow0, int k0,
                                              short* lds, int tid) {
  const int rl = tid >> 3;
  const int ks = ((tid & 7) ^ (rl & 7)) << 3;    // pre-swizzled source k
  const short* src = G + (size_t)(grow0 + rl) * K + k0 + ks;
  short* dst = lds + (tid >> 6) * 512;
  __builtin_amdgcn_global_load_lds(AS1C(src), AS3(dst), 16, 0, 0);
  __builtin_amdgcn_global_load_lds(AS1C(src + (size_t)64 * K), AS3(dst + 4096), 16, 0, 0);
}

static __device__ __forceinline__ void loadB(const float* __restrict__ B, int K,
                                             int grow0, int k0, int tid, float4* r) {
  const int row = tid >> 2;                      // 0..127 (half = 128 rows)
  const int kb = (tid & 3) << 4;                 // 0,16,32,48
  const float* s = B + (size_t)(grow0 + row) * K + k0 + kb;
  r[0] = *(const float4*)(s);
  r[1] = *(const float4*)(s + 4);
  r[2] = *(const float4*)(s + 8);
  r[3] = *(const float4*)(s + 12);
}

static __device__ __forceinline__ void writeB(short* buf, int tid, const float4* r) {
  const int row = tid >> 2;
  const int g0 = (tid & 3) << 1;                 // first 8-short granule index
  uint4 w0, w1;
  w0.x = pack_bf16_2(r[0].x, r[0].y); w0.y = pack_bf16_2(r[0].z, r[0].w);
  w0.z = pack_bf16_2(r[1].x, r[1].y); w0.w = pack_bf16_2(r[1].z, r[1].w);
  w1.x = pack_bf16_2(r[2].x, r[2].y); w1.y = pack_bf16_2(r[2].z, r[2].w);
  w1.z = pack_bf16_2(r[3].x, r[3].y); w1.w = pack_bf16_2(r[3].z, r[3].w);
  const int x = (row & 7) << 3;
  *(uint4*)(buf + row * 64 + ((g0 * 8) ^ x))       = w0;
  *(uint4*)(buf + row * 64 + (((g0 + 1) * 8) ^ x)) = w1;
}

#define MFMA16(IM0, JN0)                                                        \
  __builtin_amdgcn_s_setprio(1);                                                \
  _Pragma("unroll")                                                             \
  for (int mi = 0; mi < 4; ++mi) {                                              \
    _Pragma("unroll")                                                           \
    for (int nj = 0; nj < 2; ++nj) {                                            \
      acc[(IM0) + mi][(JN0) + nj] = __builtin_amdgcn_mfma_f32_16x16x32_bf16(    \
          a_[mi][0], b_[(JN0) + nj][0], acc[(IM0) + mi][(JN0) + nj], 0, 0, 0);  \
      acc[(IM0) + mi][(JN0) + nj] = __builtin_amdgcn_mfma_f32_16x16x32_bf16(    \
          a_[mi][1], b_[(JN0) + nj][1], acc[(IM0) + mi][(JN0) + nj], 0, 0, 0);  \
    }                                                                           \
  }                                                                             \
  __builtin_amdgcn_s_setprio(0);

__global__ __launch_bounds__(512, 2) void gemm8pf(const short* __restrict__ A,
                                                  const float* __restrict__ B,
                                                  unsigned short* __restrict__ C,
                                                  int N, int K, int mshift, int NT) {
  __shared__ __align__(16) short sA[4 * 8192];
  __shared__ __align__(16) short sB[4 * 8192];

  const int tid = threadIdx.x;
  const int lane = tid & 63;
  const int wv = tid >> 6;
  const int wm = wv >> 2;
  const int wn = wv & 3;

  const int nwg = gridDim.x;
  const int orig = blockIdx.x;
  const int q = nwg >> 3, r = nwg & 7;
  const int xcd = orig & 7;
  const int wg = (xcd < r ? xcd * (q + 1) : r * (q + 1) + (xcd - r) * q) + (orig >> 3);
  const int bm = wg & ((1 << mshift) - 1);
  const int bn = wg >> mshift;

  const int mrow0 = bm << 8;
  const int nrow0 = bn << 8;

  const int lr = lane & 15;
  const int koff0 = (((lane >> 4) << 3) ^ ((lane & 7) << 3));
  const int koff1 = ((32 + ((lane >> 4) << 3)) ^ ((lane & 7) << 3));

  f32x4 acc[8][4] = {};
  bf16x8 a_[4][2], b_[4][2];
  float4 rB0[4], rB1[4];

  // ---- prologue: A(0) via gload_lds; B(0) via regs -> pack -> LDS; B(1) regs
  stage2(A, K, mrow0,       0, sA + 0 * 8192, tid);
  stage2(A, K, mrow0 + 128, 0, sA + 1 * 8192, tid);
  loadB(B, K, nrow0,       0, tid, rB0);
  loadB(B, K, nrow0 + 128, 0, tid, rB1);
  writeB(sB + 0 * 8192, tid, rB0);   // compiler vmcnt-waits regs (forces A(0) too)
  writeB(sB + 1 * 8192, tid, rB1);
  if (NT > 1) {
    loadB(B, K, nrow0,       64, tid, rB0);
    loadB(B, K, nrow0 + 128, 64, tid, rB1);
    asm volatile("s_waitcnt vmcnt(8) lgkmcnt(0)" ::: "memory");
  } else {
    asm volatile("s_waitcnt vmcnt(0) lgkmcnt(0)" ::: "memory");
  }
  __builtin_amdgcn_s_barrier();

  for (int t = 0; t < NT; ++t) {
    const int P = t & 1;
    const short* aB = sA + (P * 2 + wm) * 8192;
    const short* bB = sB + (P * 2 + (wn >> 1)) * 8192;
    short* nxA = sA + ((P ^ 1) * 2) * 8192;
    short* nxB = sB + ((P ^ 1) * 2) * 8192;
    const int bcol = (wn & 1) * 64;

    // ---- phase a: ds_read A0 + B01; stage A0(t+1); MFMA quad(0,0)
    #pragma unroll
    for (int mi = 0; mi < 4; ++mi) {
      a_[mi][0] = *(const bf16x8*)&aB[(mi * 16 + lr) * 64 + koff0];
      a_[mi][1] = *(const bf16x8*)&aB[(mi * 16 + lr) * 64 + koff1];
    }
    #pragma unroll
    for (int nj = 0; nj < 2; ++nj) {
      const int cb = (bcol + nj * 16 + lr) * 64;
      b_[nj][0] = *(const bf16x8*)&bB[cb + koff0];
      b_[nj][1] = *(const bf16x8*)&bB[cb + koff1];
    }
    if (t + 1 < NT) stage2(A, K, mrow0, (t + 1) * 64, nxA, tid);
    __builtin_amdgcn_s_barrier();
    MFMA16(0, 0)
    __builtin_amdgcn_s_barrier();

    // ---- phase b: ds_read B23; stage A1(t+1); MFMA quad(0,2)
    #pragma unroll
    for (int nj = 0; nj < 2; ++nj) {
      const int cb = (bcol + (nj + 2) * 16 + lr) * 64;
      b_[nj + 2][0] = *(const bf16x8*)&bB[cb + koff0];
      b_[nj + 2][1] = *(const bf16x8*)&bB[cb + koff1];
    }
    if (t + 1 < NT) stage2(A, K, mrow0 + 128, (t + 1) * 64, nxA + 8192, tid);
    __builtin_amdgcn_s_barrier();
    MFMA16(0, 2)
    __builtin_amdgcn_s_barrier();

    // ---- phase c: ds_read A1; write B(t+1)h0; issue B(t+2)h0; MFMA quad(4,2)
    #pragma unroll
    for (int mi = 0; mi < 4; ++mi) {
      a_[mi][0] = *(const bf16x8*)&aB[(64 + mi * 16 + lr) * 64 + koff0];
      a_[mi][1] = *(const bf16x8*)&aB[(64 + mi * 16 + lr) * 64 + koff1];
    }
    if (t + 1 < NT) writeB(nxB, tid, rB0);
    if (t + 2 < NT) loadB(B, K, nrow0, (t + 2) * 64, tid, rB0);
    __builtin_amdgcn_s_barrier();
    MFMA16(4, 2)
    __builtin_amdgcn_s_barrier();

    // ---- phase d: write B(t+1)h1; issue B(t+2)h1; MFMA quad(4,0); boundary
    if (t + 1 < NT) writeB(nxB + 8192, tid, rB1);
    if (t + 2 < NT) loadB(B, K, nrow0 + 128, (t + 2) * 64, tid, rB1);
    __builtin_amdgcn_s_barrier();
    MFMA16(4, 0)
    if (t + 2 < NT) asm volatile("s_waitcnt vmcnt(8) lgkmcnt(0)" ::: "memory");
    else            asm volatile("s_waitcnt vmcnt(0) lgkmcnt(0)" ::: "memory");
    __builtin_amdgcn_s_barrier();
  }

  // ---- epilogue: C/D layout col=lane&15, row=(lane>>4)*4+r; bf16 store
  #pragma unroll
  for (int im = 0; im < 8; ++im) {
    const int row = mrow0 + wm * 128 + im * 16 + ((lane >> 4) << 2);
    #pragma unroll
    for (int ni = 0; ni < 4; ++ni) {
      const int col = nrow0 + wn * 64 + ni * 16 + lr;
      #pragma unroll
      for (int rr = 0; rr < 4; ++rr)
        C[(size_t)(row + rr) * N + col] = bf16_rnd(acc[im][ni][rr]);
    }
  }
}

// ---------------- 128x128 fallback GEMM (fp32 in, reg-staged bf16) -----------
__global__ __launch_bounds__(256) void gemm_lean(const float* __restrict__ A,
                                                 const float* __restrict__ B,
                                                 unsigned short* __restrict__ C,
                                                 int N, int K) {
  __shared__ __align__(16) short sA[128 * 64];
  __shared__ __align__(16) short sB[128 * 64];
  const int t = threadIdx.x;
  const int lane = t & 63;
  const int wv = t >> 6;
  const int wm = wv >> 1, wn = wv & 1;
  const int rowA0 = blockIdx.x * 128;
  const int rowB0 = blockIdx.y * 128;

  f32x4 acc[4][4] = {};

  for (int k0 = 0; k0 < K; k0 += 64) {
    #pragma unroll
    for (int i = 0; i < 8; ++i) {
      const int o = i * 1024 + t * 4;
      const int row = o >> 6;
      const int kcol = o & 63;
      const int dst = row * 64 + (kcol ^ ((row & 7) << 3));
      float4 va = *(const float4*)(A + (size_t)(rowA0 + row) * K + k0 + kcol);
      float4 vb = *(const float4*)(B + (size_t)(rowB0 + row) * K + k0 + kcol);
      uint2 pa, pb;
      pa.x = pack_bf16_2(va.x, va.y); pa.y = pack_bf16_2(va.z, va.w);
      pb.x = pack_bf16_2(vb.x, vb.y); pb.y = pack_bf16_2(vb.z, vb.w);
      *(uint2*)(sA + dst) = pa;
      *(uint2*)(sB + dst) = pb;
    }
    __syncthreads();
    #pragma unroll
    for (int kk = 0; kk < 2; ++kk) {
      bf16x8 af[4], bfr[4];
      #pragma unroll
      for (int mi = 0; mi < 4; ++mi) {
        const int row = wm * 64 + mi * 16 + (lane & 15);
        const int koff = (kk * 32 + (lane >> 4) * 8) ^ ((row & 7) << 3);
        af[mi] = *(const bf16x8*)&sA[row * 64 + koff];
      }
      #pragma unroll
      for (int ni = 0; ni < 4; ++ni) {
        const int col = wn * 64 + ni * 16 + (lane & 15);
        const int koff = (kk * 32 + (lane >> 4) * 8) ^ ((col & 7) << 3);
        bfr[ni] = *(const bf16x8*)&sB[col * 64 + koff];
      }
      #pragma unroll
      for (int mi = 0; mi < 4; ++mi)
        #pragma unroll
        for (int ni = 0; ni < 4; ++ni)
          acc[mi][ni] = __builtin_amdgcn_mfma_f32_16x16x32_bf16(af[mi], bfr[ni],
                                                                acc[mi][ni], 0, 0, 0);
    }
    __syncthreads();
  }

  #pragma unroll
  for (int mi = 0; mi < 4; ++mi)
    #pragma unroll
    for (int ni = 0; ni < 4; ++ni) {
      const int col = rowB0 + wn * 64 + ni * 16 + (lane & 15);
      const int rowb = rowA0 + wm * 64 + mi * 16 + ((lane >> 4) * 4);
      #pragma unroll
      for (int r = 0; r < 4; ++r)
        C[(size_t)(rowb + r) * N + col] = bf16_rnd(acc[mi][ni][r]);
    }
}

// ---------------- fused lse + JSD + NLL: one block per row, rows in LDS ------
__global__ __launch_bounds__(512) void fused_loss(const unsigned short* __restrict__ SL,
                                                  const unsigned short* __restrict__ TL,
                                                  int V,
                                                  const int* __restrict__ labels,
                                                  int rowOff, float* __restrict__ acc) {
  __shared__ __align__(16) unsigned short bufS[32768];
  __shared__ __align__(16) unsigned short bufT[32768];
  __shared__ float red[4][8];
  const int row = blockIdx.x;
  const int tid = threadIdx.x;
  const u16x8* ps = (const u16x8*)(SL + (size_t)row * V);
  const u16x8* pt = (const u16x8*)(TL + (size_t)row * V);
  const int n8 = V >> 3;

  float ms = -1e30f, ss = 0.f, mt = -1e30f, st = 0.f;
  for (int i = tid; i < n8; i += 512) {
    u16x8 a = ps[i], b = pt[i];
    *(u16x8*)&bufS[i * 8] = a;
    *(u16x8*)&bufT[i * 8] = b;
    float lmS = -1e30f, lmT = -1e30f;
    float fa[8], fb[8];
    #pragma unroll
    for (int j = 0; j < 8; ++j) {
      fa[j] = bf16_f(a[j]); fb[j] = bf16_f(b[j]);
      lmS = fmaxf(lmS, fa[j]); lmT = fmaxf(lmT, fb[j]);
    }
    if (lmS > ms) { ss *= __expf(ms - lmS); ms = lmS; }
    if (lmT > mt) { st *= __expf(mt - lmT); mt = lmT; }
    #pragma unroll
    for (int j = 0; j < 8; ++j) {
      ss += __expf(fa[j] - ms);
      st += __expf(fb[j] - mt);
    }
  }
  #pragma unroll
  for (int off = 32; off > 0; off >>= 1) {
    float mo = __shfl_xor(ms, off), so = __shfl_xor(ss, off);
    float mn = fmaxf(ms, mo);
    ss = ss * __expf(ms - mn) + so * __expf(mo - mn); ms = mn;
    mo = __shfl_xor(mt, off); so = __shfl_xor(st, off);
    mn = fmaxf(mt, mo);
    st = st * __expf(mt - mn) + so * __expf(mo - mn); mt = mn;
  }
  const int w = tid >> 6;
  if ((tid & 63) == 0) { red[0][w] = ms; red[1][w] = ss; red[2][w] = mt; red[3][w] = st; }
  __syncthreads();
  __shared__ float lse2[2];
  if (tid == 0) {
    float M = red[0][0], S = red[1][0];
    for (int i = 1; i < 8; ++i) {
      float mn = fmaxf(M, red[0][i]);
      S = S * __expf(M - mn) + red[1][i] * __expf(red[0][i] - mn); M = mn;
    }
    lse2[0] = M + __logf(S);
    M = red[2][0]; S = red[3][0];
    for (int i = 1; i < 8; ++i) {
      float mn = fmaxf(M, red[2][i]);
      S = S * __expf(M - mn) + red[3][i] * __expf(red[2][i] - mn); M = mn;
    }
    lse2[1] = M + __logf(S);
  }
  __syncthreads();
  const float slse = lse2[0], tlse = lse2[1];
  const int lbl = labels[rowOff + row];

  float jsd = 0.f, hard = 0.f;
  for (int i = tid; i < n8; i += 512) {
    u16x8 a = *(const u16x8*)&bufS[i * 8];
    u16x8 b = *(const u16x8*)&bufT[i * 8];
    #pragma unroll
    for (int j = 0; j < 8; ++j) {
      float sl = bf16_f(a[j]) - slse;
      float tl = bf16_f(b[j]) - tlse;
      float sp = __expf(sl), tp = __expf(tl);
      float lm = __logf(0.5f * (sp + tp));
      jsd += 0.5f * (tp * (tl - lm) + sp * (sl - lm));
      if (i * 8 + j == lbl) hard = -sl;
    }
  }
  #pragma unroll
  for (int off = 32; off > 0; off >>= 1) {
    jsd += __shfl_xor(jsd, off);
    hard += __shfl_xor(hard, off);
  }
  if ((tid & 63) == 0) { red[0][w] = jsd; red[1][w] = hard; }
  __syncthreads();
  if (tid == 0) {
    float J = 0.f, H = 0.f;
    for (int i = 0; i < 8; ++i) { J += red[0][i]; H += red[1][i]; }
    atomicAdd(&acc[0], H);
    atomicAdd(&acc[1], J);
  }
}

__global__ void finalize_loss(const float* __restrict__ acc, float* __restrict__ out,
                              float invn) {
  out[0] = 0.5f * acc[0] * invn + 0.5f * acc[1] * invn;
}

// -----------------------------------------------------------------------------
extern "C" void kernel_launch(void* const* d_in, const int* in_sizes, int n_in,
                              void* d_out, int out_size, void* d_ws, size_t ws_size,
                              hipStream_t stream) {
  const float* sIn = (const float*)d_in[0];
  const float* sW  = (const float*)d_in[1];
  const float* tIn = (const float*)d_in[2];
  const float* tW  = (const float*)d_in[3];
  const int*   lbl = (const int*)d_in[4];

  const int N  = in_sizes[4];          // 2048 tokens
  const int HS = in_sizes[0] / N;      // 2048
  const int HT = in_sizes[2] / N;      // 4096
  const int V  = in_sizes[1] / HS;     // 32000

  char* ws = (char*)d_ws;
  size_t off = 0;
  auto alloc = [&](size_t b) { size_t p = off; off = (off + b + 255) & ~(size_t)255; return p; };

  const size_t o_sInB = alloc((size_t)N * HS * 2);
  const size_t o_tInB = alloc((size_t)N * HT * 2);
  const size_t o_acc  = alloc(256);

  const bool shapeOK = (V % 256 == 0) && (V <= 32768) && (V % 8 == 0) &&
                       (HS % 64 == 0) && (HT % 64 == 0) && (N % 256 == 0);
  const size_t minLogits = 2ull * 256 * V * 2 + 512;
  const bool full = shapeOK && (off + minLogits) <= ws_size;

  size_t avail = ws_size > off ? ws_size - off : 0;
  int Rfit = (int)(avail / (2ull * V * 2));
  int R = full ? 256 : 128;
  while (R * 2 <= Rfit && R * 2 <= N) R *= 2;
  const size_t o_sL = alloc((size_t)R * V * 2);
  const size_t o_tL = alloc((size_t)R * V * 2);

  hipMemsetAsync(ws + o_acc, 0, 8, stream);

  if (full) {
    auto cvt = [&](const float* src, size_t dstOff, size_t n) {
      long long n4 = (long long)(n / 4);
      int grid = (int)((n4 + 255) / 256);
      if (grid > 2048) grid = 2048;
      cvt_f32_bf16<<<grid, 256, 0, stream>>>(src, (uint2*)(ws + dstOff), n4);
    };
    cvt(sIn, o_sInB, (size_t)N * HS);   // inputs only (~50 MB fp32)
    cvt(tIn, o_tInB, (size_t)N * HT);
  }

  const int Mt = R / 256;
  int mshift = 0;
  while ((1 << mshift) < Mt) ++mshift;

  for (int r0 = 0; r0 < N; r0 += R) {
    if (full) {
      gemm8pf<<<Mt * (V / 256), 512, 0, stream>>>(
          (const short*)(ws + o_sInB + (size_t)r0 * HS * 2), sW,
          (unsigned short*)(ws + o_sL), V, HS, mshift, HS / 64);
      gemm8pf<<<Mt * (V / 256), 512, 0, stream>>>(
          (const short*)(ws + o_tInB + (size_t)r0 * HT * 2), tW,
          (unsigned short*)(ws + o_tL), V, HT, mshift, HT / 64);
    } else {
      dim3 g(R / 128, V / 128);
      gemm_lean<<<g, 256, 0, stream>>>(sIn + (size_t)r0 * HS, sW,
                                       (unsigned short*)(ws + o_sL), V, HS);
      gemm_lean<<<g, 256, 0, stream>>>(tIn + (size_t)r0 * HT, tW,
                                       (unsigned short*)(ws + o_tL), V, HT);
    }
    fused_loss<<<R, 512, 0, stream>>>((const unsigned short*)(ws + o_sL),
                                      (const unsigned short*)(ws + o_tL), V,
                                      lbl, r0, (float*)(ws + o_acc));
  }

  finalize_loss<<<1, 1, 0, stream>>>((float*)(ws + o_acc), (float*)d_out, 1.0f / N);
}